// Round 1
// baseline (634.402 us; speedup 1.0000x reference)
//
#include <hip/hip_runtime.h>
#include <hip/hip_cooperative_groups.h>
#include <math.h>

namespace cg = cooperative_groups;

// ---------------------------------------------------------------------------
// SLAY sampled-softmax loss on MI355X — 2-dispatch version.
// R5 theory: prior 6-dispatch pipeline was gap/overhead-dominated (sum of
// per-kernel rooflines ~100us vs 396us measured, no kernel >119us).
// Now: k_setup (tiny) + ONE cooperative mega-kernel:
//   [A: embed+query features (blocks<512)  ||  B: label tiles via
//    work-stealing counter]  -> grid.sync -> [C: Z reduce] -> grid.sync
//   -> [D: denom + loss].
// Coefficients repacked [h][wave][128][24] (96B rows, 16B aligned) so the
// per-d uniform loads are 5x dwordx4 + 1 dword. slot/compaction dropped:
// feat stored for all 32768 labels (fully written, positives read in D).
// Fallback: if cooperative launch is rejected, same body split into 3
// plain dispatches (MODE 1/2/3).
// ---------------------------------------------------------------------------

namespace {
constexpr double Cq  = 2.0 + 1e-6;
constexpr double QN0 = 0.5857864376269049  / Cq;   // laggauss(2) nodes / C
constexpr double QN1 = 3.414213562373095   / Cq;
constexpr double QW0 = 0.8535533905932738  / Cq;   // laggauss(2) weights / C
constexpr double QW1 = 0.14644660940672624 / Cq;

// workspace float offsets
constexpr size_t OFF_POLYQ = 0;                      // 512*4*16   [b][h][p]
constexpr size_t OFF_PRFQ  = 32768;                  // 512*2*4*32 [b][r][h][m]
constexpr size_t OFF_Z     = OFF_PRFQ + 131072;      // 4096       [r][h][p][m]
constexpr size_t OFF_ANCT  = OFF_Z + 4096;           // 2048 anchors^T [d][p]
constexpr size_t OFF_CTR   = OFF_ANCT + 2048;        // 16 (int counter + pad)
constexpr size_t OFF_WPACK = OFF_CTR + 16;           // 4*4*128*24 = 49152
constexpr size_t OFF_ZPART = OFF_WPACK + 49152;      // 2048*1024 Z partials
constexpr size_t OFF_FEAT  = OFF_ZPART + 2097152;    // 32768*4*80 label feats
}

// grid-parallel init: Z=0, out=0, ctr=0, anchors^T, Wpack[h][w][128][24]
__global__ void k_setup(const float* __restrict__ anchors,
                        const float* __restrict__ omega,
                        float* __restrict__ Z, float* __restrict__ out,
                        float* __restrict__ anct, int* __restrict__ ctr,
                        float* __restrict__ Wpack)
{
    int t = blockIdx.x * 256 + threadIdx.x;           // 64*256 = 16384 threads
    if (t < 4096) Z[t] = 0.f;
    if (t == 0) { out[0] = 0.f; ctr[0] = 0; }
    if (t < 2048) {                                   // anct[d][p]
        int p = t & 15, d = t >> 4;
        anct[t] = anchors[p * 128 + d];
    }
    for (int i = t; i < 4 * 4 * 128 * 24; i += 16384) {
        int iw = i % 24;
        int hwd = i / 24;                             // (h*4+w)*128 + d
        int d = hwd & 127;
        int hw = hwd >> 7;
        int w = hw & 3, h = hw >> 2;
        int o = w * 21 + iw;
        float v = 0.f;
        if (iw < 21 && o < 80) {
            if (o < 16) v = anchors[o * 128 + d];
            else {
                int r = (o - 16) >> 5, m = (o - 16) & 31;
                v = omega[(((r * 4 + h) * 128) + d) * 32 + m];
            }
        }
        Wpack[i] = v;
    }
}

// MODE 0: full cooperative (A||B -> sync -> C -> sync -> D), grid 1024x256.
// MODE 1: A||B only (grid 1024). MODE 2: C only (grid 128). MODE 3: D (128).
template<int MODE>
__global__ void __launch_bounds__(256, 4)
k_mega(const int* __restrict__ idx, const float* __restrict__ mask,
       const int* __restrict__ labels, const float* __restrict__ lmask,
       const float* __restrict__ emb, const float* __restrict__ ck,
       const float* __restrict__ omega, const float* __restrict__ anct,
       const float* __restrict__ Wpack, int* __restrict__ ctr,
       float* __restrict__ polyq, float* __restrict__ prfq,
       float* __restrict__ Z, float* __restrict__ Zpart,
       float* __restrict__ feat, float* __restrict__ out)
{
    __shared__ float smem[8192];    // B: x-tile [128][64]; aliased ex[64][85]
    __shared__ float rnS[4];        // A: per-head inv-norms
    __shared__ int   sTile;         // B: work-stealing tile id

    int t = threadIdx.x;
    int lane = t & 63;
    int w = t >> 6;

    const float s_[2] = {(float)QN0, (float)QN1};
    const float g_[2] = {sqrtf(2.0f * (float)QN0), sqrtf(2.0f * (float)QN1)};
    const float c_[2] = {sqrtf((float)QW0) * 0.17677669529663687f,
                         sqrtf((float)QW1) * 0.17677669529663687f};

    if (MODE == 0 || MODE == 1) {
        // ---------------- phase A: mean embedding -> query features -------
        if (blockIdx.x < 512) {
            int b = blockIdx.x;
            float2 acc = make_float2(0.f, 0.f);
            float msum = 0.f;
#pragma unroll 8
            for (int s = 0; s < 64; ++s) {
                float mv = mask[b * 64 + s];
                const float2* row = (const float2*)(emb + (size_t)idx[b * 64 + s] * 512);
                float2 v = row[t];
                acc.x = fmaf(mv, v.x, acc.x);
                acc.y = fmaf(mv, v.y, acc.y);
                msum += mv;
            }
            float inv = 1.0f / fmaxf(msum, 1e-9f);
            smem[2 * t]     = acc.x * inv;
            smem[2 * t + 1] = acc.y * inv;
            __syncthreads();
            {
                float v0 = smem[w * 128 + lane], v1 = smem[w * 128 + 64 + lane];
                float ss = fmaf(v0, v0, v1 * v1);
#pragma unroll
                for (int o = 1; o < 64; o <<= 1) ss += __shfl_xor(ss, o, 64);
                if (lane == 0) rnS[w] = 1.0f / fmaxf(sqrtf(ss), 1e-6f);
            }
            __syncthreads();
            for (int tau = t; tau < 320; tau += 256) {
                int h = tau / 80, j = tau - h * 80;
                const float* xh = smem + h * 128;
                if (j < 16) {
                    float a = 0.f;
                    for (int d = 0; d < 128; ++d) a = fmaf(xh[d], anct[d * 16 + j], a);
                    float v = a * rnS[h];
                    polyq[(b * 4 + h) * 16 + j] = v * v * 0.25f;
                } else {
                    int rj = j - 16, r = rj >> 5, m = rj & 31;
                    const float* om = omega + ((size_t)(r * 4 + h) * 128) * 32 + m;
                    float a = 0.f;
                    for (int d = 0; d < 128; ++d) a = fmaf(xh[d], om[d * 32], a);
                    float z = a * rnS[h] * g_[r] - s_[r];
                    z = fminf(fmaxf(z, -10.f), 10.f);
                    prfq[((b * 2 + r) * 4 + h) * 32 + m] = expf(z) * c_[r];
                }
            }
            __syncthreads();          // smem handoff to phase B
        }

        // ---------------- phase B: label tiles via work stealing ----------
        int wu = __builtin_amdgcn_readfirstlane(w);
        while (true) {
            if (t == 0) sTile = atomicAdd(ctr, 1);
            __syncthreads();
            int tile = sTile;
            if (tile >= 2048) break;
            int g = tile >> 2, h = tile & 3;
            int l0 = g << 6;

            // stage x tile [d=128][lab=64] (coalesced 256B/wave rows)
            {
                const float* src = ck + (size_t)h * 128 * 32768 + l0;
#pragma unroll
                for (int k2 = 0; k2 < 32; ++k2) {
                    int ix = k2 * 256 + t;            // d = ix>>6, lab = ix&63
                    int d = ix >> 6, lab = ix & 63;
                    smem[ix] = src[(size_t)d * 32768 + lab];
                }
            }
            __syncthreads();

            // 21 outputs per wave; coeffs from 16B-aligned [128][24] slice
            const float* wv = Wpack + ((size_t)(h * 4 + wu) * 128) * 24;
            float acc[21] = {};
            float sumsq = 0.f;
            for (int d = 0; d < 128; ++d) {
                float xv = smem[d * 64 + lane];
                sumsq = fmaf(xv, xv, sumsq);
                const float* c = wv + d * 24;
                float4 c0 = *(const float4*)(c);
                float4 c1 = *(const float4*)(c + 4);
                float4 c2 = *(const float4*)(c + 8);
                float4 c3 = *(const float4*)(c + 12);
                float4 c4 = *(const float4*)(c + 16);
                float cl = c[20];
                acc[0]  = fmaf(xv, c0.x, acc[0]);  acc[1]  = fmaf(xv, c0.y, acc[1]);
                acc[2]  = fmaf(xv, c0.z, acc[2]);  acc[3]  = fmaf(xv, c0.w, acc[3]);
                acc[4]  = fmaf(xv, c1.x, acc[4]);  acc[5]  = fmaf(xv, c1.y, acc[5]);
                acc[6]  = fmaf(xv, c1.z, acc[6]);  acc[7]  = fmaf(xv, c1.w, acc[7]);
                acc[8]  = fmaf(xv, c2.x, acc[8]);  acc[9]  = fmaf(xv, c2.y, acc[9]);
                acc[10] = fmaf(xv, c2.z, acc[10]); acc[11] = fmaf(xv, c2.w, acc[11]);
                acc[12] = fmaf(xv, c3.x, acc[12]); acc[13] = fmaf(xv, c3.y, acc[13]);
                acc[14] = fmaf(xv, c3.z, acc[14]); acc[15] = fmaf(xv, c3.w, acc[15]);
                acc[16] = fmaf(xv, c4.x, acc[16]); acc[17] = fmaf(xv, c4.y, acc[17]);
                acc[18] = fmaf(xv, c4.z, acc[18]); acc[19] = fmaf(xv, c4.w, acc[19]);
                acc[20] = fmaf(xv, cl,   acc[20]);
            }
            __syncthreads();          // all waves done reading x tile

            // exchange into ex[label][85] (aliases smem)
            int o0 = wu * 21;
#pragma unroll
            for (int i = 0; i < 21; ++i) {
                int o = o0 + i;
                if (o < 80) smem[lane * 85 + o] = acc[i];
            }
            if (wu == 3) smem[lane * 85 + 80] = sumsq;
            __syncthreads();

            // finalize in place: thread (l = t&63, part = t>>6) -> 20 outputs
            {
                int l = t & 63, part = t >> 6, of = part * 20;
                float rn = 1.0f / fmaxf(sqrtf(smem[l * 85 + 80]), 1e-6f);
#pragma unroll
                for (int i = 0; i < 20; ++i) {
                    int o = of + i;
                    float v = smem[l * 85 + o];
                    if (o < 16) {
                        v = v * rn;
                        v = v * v * 0.25f;
                    } else {
                        int r = (o - 16) >> 5;
                        float z = v * rn * g_[r] - s_[r];
                        z = fminf(fmaxf(z, -10.f), 10.f);
                        v = expf(z) * c_[r];
                    }
                    smem[l * 85 + o] = v;
                }
            }
            __syncthreads();

            // full feature store (all 64 labels x 80 outputs)
            for (int e = t; e < 5120; e += 256) {
                int j = e / 80, o = e - j * 80;
                feat[((size_t)(l0 + j) * 4 + h) * 80 + o] = smem[j * 85 + o];
            }

            // Z partial: thread (t<128) owns (r, p0, m0)
            if (t < 128) {
                int r = t >> 6, p0 = ((t >> 3) & 7) * 2, m0 = (t & 7) * 4;
                float z0[4] = {}, z1[4] = {};
                for (int j = 0; j < 64; ++j) {
                    const float* row = smem + j * 85;
                    float pa = row[p0], pb = row[p0 + 1];
                    const float* pf = row + 16 + r * 32 + m0;
#pragma unroll
                    for (int k2 = 0; k2 < 4; ++k2) {
                        float fv = pf[k2];
                        z0[k2] = fmaf(pa, fv, z0[k2]);
                        z1[k2] = fmaf(pb, fv, z1[k2]);
                    }
                }
                float* zp = Zpart + (size_t)tile * 1024;
#pragma unroll
                for (int k2 = 0; k2 < 4; ++k2) {
                    zp[(r * 16 + p0) * 32 + m0 + k2]     = z0[k2];
                    zp[(r * 16 + p0 + 1) * 32 + m0 + k2] = z1[k2];
                }
            }
            __syncthreads();          // protect smem + sTile for next tile
        }
    }

    if (MODE == 0) cg::this_grid().sync();

    if (MODE == 0 || MODE == 2) {
        // ---------------- phase C: reduce Zpart -> Z ----------------------
        if (blockIdx.x < 128) {
            int tid = blockIdx.x * 256 + t;           // 32768 threads
            int e = tid & 1023, h = (tid >> 10) & 3, chunk = tid >> 12;
            float sum = 0.f;
            int g0 = chunk * 64;
#pragma unroll 4
            for (int g = g0; g < g0 + 64; ++g)
                sum += Zpart[(size_t)((g << 2) | h) * 1024 + e];
            atomicAdd(&Z[(e >> 9) * 2048 + h * 512 + (e & 511)], sum);
        }
    }

    if (MODE == 0) cg::this_grid().sync();

    if (MODE == 0 || MODE == 3) {
        // ---------------- phase D: denom + loss (one wave per b) ----------
        if (blockIdx.x < 128) {
            int b = blockIdx.x * 4 + w;

            float acc = 0.f;
            for (int i = 0; i < 64; ++i) {
                int f = i * 64 + lane;                 // coalesced Z reads
                int m = f & 31, p = (f >> 5) & 15, hh = (f >> 9) & 3, r = f >> 11;
                float phi = polyq[(b * 4 + hh) * 16 + p] *
                            prfq[((b * 2 + r) * 4 + hh) * 32 + m];
                acc = fmaf(phi, Z[f], acc);
            }
#pragma unroll
            for (int o = 1; o < 64; o <<= 1) acc += __shfl_xor(acc, o, 64);
            float logZb = logf(acc + 1e-6f);

            if (lane < 20) {                           // lane = k*4 + h
                int k = lane >> 2, h = lane & 3;
                int l = max(labels[b * 5 + k], 0);
                const float4* f4 = (const float4*)(feat + ((size_t)l * 4 + h) * 80);
                const float* pq = polyq + (b * 4 + h) * 16;
                const float* q0 = prfq + ((b * 2 + 0) * 4 + h) * 32;
                const float* q1 = prfq + ((b * 2 + 1) * 4 + h) * 32;

                float pd = 0.f;
#pragma unroll
                for (int j = 0; j < 4; ++j) {
                    float4 fp = f4[j];
                    pd = fmaf(fp.x, pq[4*j+0], pd);
                    pd = fmaf(fp.y, pq[4*j+1], pd);
                    pd = fmaf(fp.z, pq[4*j+2], pd);
                    pd = fmaf(fp.w, pq[4*j+3], pd);
                }
                float f0 = 0.f, f1 = 0.f;
#pragma unroll
                for (int j = 0; j < 8; ++j) {
                    float4 fv = f4[4 + j];
                    f0 = fmaf(fv.x, q0[4*j+0], f0);
                    f0 = fmaf(fv.y, q0[4*j+1], f0);
                    f0 = fmaf(fv.z, q0[4*j+2], f0);
                    f0 = fmaf(fv.w, q0[4*j+3], f0);
                    float4 fw = f4[12 + j];
                    f1 = fmaf(fw.x, q1[4*j+0], f1);
                    f1 = fmaf(fw.y, q1[4*j+1], f1);
                    f1 = fmaf(fw.z, q1[4*j+2], f1);
                    f1 = fmaf(fw.w, q1[4*j+3], f1);
                }
                float c = pd * (f0 + f1);
                c += __shfl_xor(c, 1, 64);             // sum the 4 heads
                c += __shfl_xor(c, 2, 64);
                if (h == 0) {
                    float val = (logf(c + 1e-6f) - logZb) * lmask[b * 5 + k];
                    atomicAdd(out, val * (-1.0f / 512.0f));
                }
            }
        }
    }
}

extern "C" void kernel_launch(void* const* d_in, const int* in_sizes, int n_in,
                              void* d_out, int out_size, void* d_ws, size_t ws_size,
                              hipStream_t stream)
{
    const int*   indices = (const int*)  d_in[0];
    const float* mask    = (const float*)d_in[1];
    const int*   labels  = (const int*)  d_in[2];
    const float* lmask   = (const float*)d_in[3];
    const float* emb     = (const float*)d_in[4];
    const float* ck      = (const float*)d_in[5];   // [512][32768]
    const float* omega   = (const float*)d_in[6];   // [2][4][128][32]
    const float* anchors = (const float*)d_in[7];   // [16][128]
    float* ws  = (float*)d_ws;
    float* out = (float*)d_out;

    float* polyq = ws + OFF_POLYQ;
    float* prfq  = ws + OFF_PRFQ;
    float* Zp    = ws + OFF_Z;
    float* anct  = ws + OFF_ANCT;
    int*   ctr   = (int*)(ws + OFF_CTR);
    float* Wpack = ws + OFF_WPACK;
    float* Zpart = ws + OFF_ZPART;
    float* feat  = ws + OFF_FEAT;

    k_setup<<<64, 256, 0, stream>>>(anchors, omega, Zp, out, anct, ctr, Wpack);

    const int*   a_idx   = indices;  const float* a_mask = mask;
    const int*   a_lab   = labels;   const float* a_lm   = lmask;
    const float* a_emb   = emb;      const float* a_ck   = ck;
    const float* a_om    = omega;    const float* a_anct = anct;
    const float* a_wp    = Wpack;    int*         a_ctr  = ctr;
    float* a_pq = polyq; float* a_pr = prfq; float* a_z = Zp;
    float* a_zp = Zpart; float* a_ft = feat; float* a_out = out;
    void* args[] = { &a_idx, &a_mask, &a_lab, &a_lm, &a_emb, &a_ck, &a_om,
                     &a_anct, &a_wp, &a_ctr, &a_pq, &a_pr, &a_z, &a_zp,
                     &a_ft, &a_out };

    hipError_t e = hipLaunchCooperativeKernel(
        reinterpret_cast<void*>(&k_mega<0>), dim3(1024), dim3(256),
        args, 0, stream);

    if (e != hipSuccess) {
        (void)hipGetLastError();    // clear; fall back to 3 plain dispatches
        k_mega<1><<<1024, 256, 0, stream>>>(indices, mask, labels, lmask, emb,
            ck, omega, anct, Wpack, ctr, polyq, prfq, Zp, Zpart, feat, out);
        k_mega<2><<<128, 256, 0, stream>>>(indices, mask, labels, lmask, emb,
            ck, omega, anct, Wpack, ctr, polyq, prfq, Zp, Zpart, feat, out);
        k_mega<3><<<128, 256, 0, stream>>>(indices, mask, labels, lmask, emb,
            ck, omega, anct, Wpack, ctr, polyq, prfq, Zp, Zpart, feat, out);
    }
}

// Round 2
// 398.065 us; speedup vs baseline: 1.5937x; 1.5937x over previous
//
#include <hip/hip_runtime.h>
#include <math.h>

// ---------------------------------------------------------------------------
// SLAY sampled-softmax loss on MI355X — 3-dispatch static version.
// R6 post-mortem of R5: work-stealing tile id came from LDS -> compiler could
// not prove wave-uniformity -> Wpack coefficient loads fell off the scalar
// (s_load) path onto per-lane VMEM, putting L2 latency in the d-loop critical
// path (VALUBusy 10%, HBM 6%, 385us). Cooperative launch added overhead and
// bought nothing.
// Now: tile/h derived from blockIdx (SGPR) exactly like the proven-fast
// k_labels; A (embed+query feats) fused as blocks 0..511 of the same dispatch
// (overlaps B, no extra node); Zpart buffer + reduce dispatch replaced by
// direct atomicAdd into Z[4096] (2M atomics over 4096 addrs, negligible).
// Pipeline: k_setup -> k_ab -> k_final.
// ---------------------------------------------------------------------------

namespace {
constexpr double Cq  = 2.0 + 1e-6;
constexpr double QN0 = 0.5857864376269049  / Cq;   // laggauss(2) nodes / C
constexpr double QN1 = 3.414213562373095   / Cq;
constexpr double QW0 = 0.8535533905932738  / Cq;   // laggauss(2) weights / C
constexpr double QW1 = 0.14644660940672624 / Cq;

// workspace float offsets
constexpr size_t OFF_POLYQ = 0;                      // 512*4*16   [b][h][p]
constexpr size_t OFF_PRFQ  = 32768;                  // 512*2*4*32 [b][r][h][m]
constexpr size_t OFF_Z     = OFF_PRFQ + 131072;      // 4096       [r][h][p][m]
constexpr size_t OFF_ANCT  = OFF_Z + 4096;           // 2048 anchors^T [d][p]
constexpr size_t OFF_WPACK = OFF_ANCT + 2048;        // 4*4*128*24 = 49152
constexpr size_t OFF_FEAT  = OFF_WPACK + 49152;      // 32768*4*80 label feats
}

// grid-parallel init: Z=0, out=0, anchors^T, Wpack[h][w][128][24] (16B rows)
__global__ void k_setup(const float* __restrict__ anchors,
                        const float* __restrict__ omega,
                        float* __restrict__ Z, float* __restrict__ out,
                        float* __restrict__ anct, float* __restrict__ Wpack)
{
    int t = blockIdx.x * 256 + threadIdx.x;           // 64*256 = 16384 threads
    if (t < 4096) Z[t] = 0.f;
    if (t == 0) out[0] = 0.f;
    if (t < 2048) {                                   // anct[d][p]
        int p = t & 15, d = t >> 4;
        anct[t] = anchors[p * 128 + d];
    }
    for (int i = t; i < 4 * 4 * 128 * 24; i += 16384) {
        int iw = i % 24;
        int hwd = i / 24;                             // (h*4+w)*128 + d
        int d = hwd & 127;
        int hw = hwd >> 7;
        int w = hw & 3, h = hw >> 2;
        int o = w * 21 + iw;
        float v = 0.f;
        if (iw < 21 && o < 80) {
            if (o < 16) v = anchors[o * 128 + d];
            else {
                int r = (o - 16) >> 5, m = (o - 16) & 31;
                v = omega[(((r * 4 + h) * 128) + d) * 32 + m];
            }
        }
        Wpack[i] = v;
    }
}

// Fused A||B, grid 2560 x 256.
// Blocks 0..511   = phase A: mean embedding -> query features (polyq/prfq).
// Blocks 512..2559 = phase B: one 64-label x 1-head tile each;
//   tile = bid-512, h = bid & 3 (SGPR -> Wpack loads stay on the scalar path).
__global__ void __launch_bounds__(256, 4)
k_ab(const int* __restrict__ idx, const float* __restrict__ mask,
     const float* __restrict__ emb, const float* __restrict__ ck,
     const float* __restrict__ omega, const float* __restrict__ anct,
     const float* __restrict__ Wpack,
     float* __restrict__ polyq, float* __restrict__ prfq,
     float* __restrict__ Z, float* __restrict__ feat)
{
    __shared__ float smem[8192];    // B: x-tile [128][64]; aliased ex[64][85]
    __shared__ float rnS[4];        // A: per-head inv-norms

    int t = threadIdx.x;
    int lane = t & 63;
    int w = t >> 6;
    int bid = blockIdx.x;

    const float s_[2] = {(float)QN0, (float)QN1};
    const float g_[2] = {sqrtf(2.0f * (float)QN0), sqrtf(2.0f * (float)QN1)};
    const float c_[2] = {sqrtf((float)QW0) * 0.17677669529663687f,
                         sqrtf((float)QW1) * 0.17677669529663687f};

    if (bid < 512) {
        // ---------------- phase A: mean embedding -> query features -------
        int b = bid;
        float2 acc = make_float2(0.f, 0.f);
        float msum = 0.f;
#pragma unroll 8
        for (int s = 0; s < 64; ++s) {
            float mv = mask[b * 64 + s];
            const float2* row = (const float2*)(emb + (size_t)idx[b * 64 + s] * 512);
            float2 v = row[t];
            acc.x = fmaf(mv, v.x, acc.x);
            acc.y = fmaf(mv, v.y, acc.y);
            msum += mv;
        }
        float inv = 1.0f / fmaxf(msum, 1e-9f);
        smem[2 * t]     = acc.x * inv;
        smem[2 * t + 1] = acc.y * inv;
        __syncthreads();
        {
            float v0 = smem[w * 128 + lane], v1 = smem[w * 128 + 64 + lane];
            float ss = fmaf(v0, v0, v1 * v1);
#pragma unroll
            for (int o = 1; o < 64; o <<= 1) ss += __shfl_xor(ss, o, 64);
            if (lane == 0) rnS[w] = 1.0f / fmaxf(sqrtf(ss), 1e-6f);
        }
        __syncthreads();
        for (int tau = t; tau < 320; tau += 256) {
            int h = tau / 80, j = tau - h * 80;
            const float* xh = smem + h * 128;
            if (j < 16) {
                float a = 0.f;
                for (int d = 0; d < 128; ++d) a = fmaf(xh[d], anct[d * 16 + j], a);
                float v = a * rnS[h];
                polyq[(b * 4 + h) * 16 + j] = v * v * 0.25f;
            } else {
                int rj = j - 16, r = rj >> 5, m = rj & 31;
                const float* om = omega + ((size_t)(r * 4 + h) * 128) * 32 + m;
                float a = 0.f;
                for (int d = 0; d < 128; ++d) a = fmaf(xh[d], om[d * 32], a);
                float z = a * rnS[h] * g_[r] - s_[r];
                z = fminf(fmaxf(z, -10.f), 10.f);
                prfq[((b * 2 + r) * 4 + h) * 32 + m] = expf(z) * c_[r];
            }
        }
        return;
    }

    // ---------------- phase B: one label tile ------------------------------
    int tile = bid - 512;                    // 512 % 4 == 0 -> h = bid & 3
    int g = tile >> 2, h = tile & 3;
    int l0 = g << 6;

    // stage x tile [d=128][lab=64] (coalesced 256B/wave rows)
    {
        const float* src = ck + (size_t)h * 128 * 32768 + l0;
#pragma unroll
        for (int k2 = 0; k2 < 32; ++k2) {
            int ix = k2 * 256 + t;            // d = ix>>6, lab = ix&63
            int d = ix >> 6, lab = ix & 63;
            smem[ix] = src[(size_t)d * 32768 + lab];
        }
    }
    __syncthreads();

    // 21 outputs per wave; coeffs from 16B-aligned scalar (SGPR) addresses
    int wu = __builtin_amdgcn_readfirstlane(w);
    const float* wv = Wpack + ((size_t)((h << 2) | wu) * 128) * 24;
    float acc[21] = {};
    float sumsq = 0.f;
    for (int d = 0; d < 128; ++d) {
        float xv = smem[d * 64 + lane];
        sumsq = fmaf(xv, xv, sumsq);
        const float* c = wv + d * 24;
        float4 c0 = *(const float4*)(c);
        float4 c1 = *(const float4*)(c + 4);
        float4 c2 = *(const float4*)(c + 8);
        float4 c3 = *(const float4*)(c + 12);
        float4 c4 = *(const float4*)(c + 16);
        float cl = c[20];
        acc[0]  = fmaf(xv, c0.x, acc[0]);  acc[1]  = fmaf(xv, c0.y, acc[1]);
        acc[2]  = fmaf(xv, c0.z, acc[2]);  acc[3]  = fmaf(xv, c0.w, acc[3]);
        acc[4]  = fmaf(xv, c1.x, acc[4]);  acc[5]  = fmaf(xv, c1.y, acc[5]);
        acc[6]  = fmaf(xv, c1.z, acc[6]);  acc[7]  = fmaf(xv, c1.w, acc[7]);
        acc[8]  = fmaf(xv, c2.x, acc[8]);  acc[9]  = fmaf(xv, c2.y, acc[9]);
        acc[10] = fmaf(xv, c2.z, acc[10]); acc[11] = fmaf(xv, c2.w, acc[11]);
        acc[12] = fmaf(xv, c3.x, acc[12]); acc[13] = fmaf(xv, c3.y, acc[13]);
        acc[14] = fmaf(xv, c3.z, acc[14]); acc[15] = fmaf(xv, c3.w, acc[15]);
        acc[16] = fmaf(xv, c4.x, acc[16]); acc[17] = fmaf(xv, c4.y, acc[17]);
        acc[18] = fmaf(xv, c4.z, acc[18]); acc[19] = fmaf(xv, c4.w, acc[19]);
        acc[20] = fmaf(xv, cl,   acc[20]);
    }
    __syncthreads();                  // all waves done reading x tile

    // exchange into ex[label][85] (aliases smem)
    int o0 = wu * 21;
#pragma unroll
    for (int i = 0; i < 21; ++i) {
        int o = o0 + i;
        if (o < 80) smem[lane * 85 + o] = acc[i];
    }
    if (wu == 3) smem[lane * 85 + 80] = sumsq;
    __syncthreads();

    // finalize in place: thread (l = t&63, part = t>>6) -> 20 outputs
    {
        int l = t & 63, part = t >> 6, of = part * 20;
        float rn = 1.0f / fmaxf(sqrtf(smem[l * 85 + 80]), 1e-6f);
#pragma unroll
        for (int i = 0; i < 20; ++i) {
            int o = of + i;
            float v = smem[l * 85 + o];
            if (o < 16) {
                v = v * rn;
                v = v * v * 0.25f;
            } else {
                int r = (o - 16) >> 5;
                float z = v * rn * g_[r] - s_[r];
                z = fminf(fmaxf(z, -10.f), 10.f);
                v = expf(z) * c_[r];
            }
            smem[l * 85 + o] = v;
        }
    }
    __syncthreads();

    // full feature store (all 64 labels x 80 outputs)
    for (int e = t; e < 5120; e += 256) {
        int j = e / 80, o = e - j * 80;
        feat[((size_t)(l0 + j) * 4 + h) * 80 + o] = smem[j * 85 + o];
    }

    // Z partial: thread (t<128) owns (r, p0, m0); atomic straight into Z
    if (t < 128) {
        int r = t >> 6, p0 = ((t >> 3) & 7) * 2, m0 = (t & 7) * 4;
        float z0[4] = {}, z1[4] = {};
        for (int j = 0; j < 64; ++j) {
            const float* row = smem + j * 85;
            float pa = row[p0], pb = row[p0 + 1];
            const float* pf = row + 16 + r * 32 + m0;
#pragma unroll
            for (int k2 = 0; k2 < 4; ++k2) {
                float fv = pf[k2];
                z0[k2] = fmaf(pa, fv, z0[k2]);
                z1[k2] = fmaf(pb, fv, z1[k2]);
            }
        }
        // Z flat layout [r][h][p][m]
        float* zb = Z + ((size_t)(r * 4 + h) * 16) * 32;
#pragma unroll
        for (int k2 = 0; k2 < 4; ++k2) {
            atomicAdd(&zb[p0 * 32 + m0 + k2],       z0[k2]);
            atomicAdd(&zb[(p0 + 1) * 32 + m0 + k2], z1[k2]);
        }
    }
}

// fused denom + loss: one wave per batch row b (grid 128 x 256)
__global__ void k_final(const float* __restrict__ polyq, const float* __restrict__ prfq,
                        const float* __restrict__ Z, const int* __restrict__ labels,
                        const float* __restrict__ lmask,
                        const float* __restrict__ feat, float* __restrict__ out)
{
    int t = threadIdx.x, lane = t & 63;
    int b = blockIdx.x * 4 + (t >> 6);

    float acc = 0.f;
    for (int i = 0; i < 64; ++i) {
        int f = i * 64 + lane;                         // coalesced Z reads
        int m = f & 31, p = (f >> 5) & 15, hh = (f >> 9) & 3, r = f >> 11;
        float phi = polyq[(b * 4 + hh) * 16 + p] * prfq[((b * 2 + r) * 4 + hh) * 32 + m];
        acc = fmaf(phi, Z[f], acc);
    }
#pragma unroll
    for (int o = 1; o < 64; o <<= 1) acc += __shfl_xor(acc, o, 64);
    float logZb = logf(acc + 1e-6f);                   // all lanes hold the sum

    if (lane < 20) {                                   // lane = k*4 + h
        int k = lane >> 2, h = lane & 3;
        int l = max(labels[b * 5 + k], 0);
        const float4* f4 = (const float4*)(feat + ((size_t)l * 4 + h) * 80);
        const float* pq = polyq + (b * 4 + h) * 16;
        const float* q0 = prfq + ((b * 2 + 0) * 4 + h) * 32;
        const float* q1 = prfq + ((b * 2 + 1) * 4 + h) * 32;

        float pd = 0.f;
#pragma unroll
        for (int j = 0; j < 4; ++j) {
            float4 fp = f4[j];
            pd = fmaf(fp.x, pq[4*j+0], pd);
            pd = fmaf(fp.y, pq[4*j+1], pd);
            pd = fmaf(fp.z, pq[4*j+2], pd);
            pd = fmaf(fp.w, pq[4*j+3], pd);
        }
        float f0 = 0.f, f1 = 0.f;
#pragma unroll
        for (int j = 0; j < 8; ++j) {
            float4 fv = f4[4 + j];
            f0 = fmaf(fv.x, q0[4*j+0], f0);
            f0 = fmaf(fv.y, q0[4*j+1], f0);
            f0 = fmaf(fv.z, q0[4*j+2], f0);
            f0 = fmaf(fv.w, q0[4*j+3], f0);
            float4 fw = f4[12 + j];
            f1 = fmaf(fw.x, q1[4*j+0], f1);
            f1 = fmaf(fw.y, q1[4*j+1], f1);
            f1 = fmaf(fw.z, q1[4*j+2], f1);
            f1 = fmaf(fw.w, q1[4*j+3], f1);
        }
        float c = pd * (f0 + f1);
        c += __shfl_xor(c, 1, 64);                     // sum the 4 heads
        c += __shfl_xor(c, 2, 64);
        if (h == 0) {
            float val = (logf(c + 1e-6f) - logZb) * lmask[b * 5 + k];
            atomicAdd(out, val * (-1.0f / 512.0f));
        }
    }
}

extern "C" void kernel_launch(void* const* d_in, const int* in_sizes, int n_in,
                              void* d_out, int out_size, void* d_ws, size_t ws_size,
                              hipStream_t stream)
{
    const int*   indices = (const int*)  d_in[0];
    const float* mask    = (const float*)d_in[1];
    const int*   labels  = (const int*)  d_in[2];
    const float* lmask   = (const float*)d_in[3];
    const float* emb     = (const float*)d_in[4];
    const float* ck      = (const float*)d_in[5];   // [512][32768]
    const float* omega   = (const float*)d_in[6];   // [2][4][128][32]
    const float* anchors = (const float*)d_in[7];   // [16][128]
    float* ws  = (float*)d_ws;
    float* out = (float*)d_out;

    float* polyq = ws + OFF_POLYQ;
    float* prfq  = ws + OFF_PRFQ;
    float* Zp    = ws + OFF_Z;
    float* anct  = ws + OFF_ANCT;
    float* Wpack = ws + OFF_WPACK;
    float* feat  = ws + OFF_FEAT;

    k_setup<<<64, 256, 0, stream>>>(anchors, omega, Zp, out, anct, Wpack);
    k_ab<<<2560, 256, 0, stream>>>(indices, mask, emb, ck, omega, anct, Wpack,
                                   polyq, prfq, Zp, feat);
    k_final<<<128, 256, 0, stream>>>(polyq, prfq, Zp, labels, lmask, feat, out);
}